// Round 12
// baseline (277.763 us; speedup 1.0000x reference)
//
#include <hip/hip_runtime.h>
#include <hip/hip_bf16.h>

#define C 64   // C_IN == C_OUT == 64
#define FXSCALE 16777216.0f            // 2^24
#define LOW44 ((1ULL << 44) - 1)
#define FGRID 256                      // front-end persistent grid (1 block/CU safe)
#define FT (FGRID * 256)

typedef unsigned short u16;

__device__ __forceinline__ u16 f2bf_rne(float v) {
    unsigned u = __float_as_uint(v);
    u += 0x7FFFu + ((u >> 16) & 1u);
    return (u16)(u >> 16);
}
__device__ __forceinline__ float bf2f(u16 u) {
    return __uint_as_float((unsigned)u << 16);
}

// Device-scope grid barrier: all FGRID blocks are co-resident (grid <= #CUs).
__device__ __forceinline__ void gridbar(int* cnt, int target) {
    __syncthreads();
    if (threadIdx.x == 0) {
        __threadfence();                       // release
        atomicAdd(cnt, 1);
        while (atomicAdd(cnt, 0) < target) {   // device-coherent RMW spin
            __builtin_amdgcn_s_sleep(2);
        }
        __threadfence();                       // acquire
    }
    __syncthreads();
}

// --- Persistent front-end: hist -> scans -> (rowptr,xg) -> scatter ---
// barcnt and cd are pre-zeroed by one hipMemsetAsync.
__global__ __launch_bounds__(256) void frontend_kernel(
        const float* __restrict__ x,
        const int* __restrict__ row,
        const int* __restrict__ col,
        const float* __restrict__ ew,
        int* __restrict__ barcnt,
        unsigned long long* __restrict__ cd,
        int* __restrict__ rowptr,
        int* __restrict__ bsum,
        u16* __restrict__ rank16,
        unsigned* __restrict__ epk,
        float* __restrict__ dis,
        u16* __restrict__ xg,
        int E, int N) {
    __shared__ int s[256];
    int t = threadIdx.x;
    int bid = blockIdx.x;
    int gtid = bid * 256 + t;
    const int G = (N + 255) / 256;   // row chunks (196 <= FGRID)

    // ---- phase 1: histogram (one u64 atomic per edge) + rank ----
    for (int e = gtid; e < E; e += FT) {
        int r = row[e];
        unsigned long long fx = (unsigned long long)__float2uint_rn(ew[e] * FXSCALE);
        unsigned long long old = atomicAdd(&cd[r], (1ULL << 44) | fx);
        rank16[e] = (u16)(old >> 44);
    }
    gridbar(barcnt, 1 * FGRID);

    // ---- phase 2a: per-chunk sums -> bsum; dis = rsqrt(deg) ----
    if (bid < G) {
        int i = bid * 256 + t;
        int cv = 0;
        if (i < N) {
            unsigned long long v = cd[i];
            cv = (int)(v >> 44);
            float dv = (float)(v & LOW44) * (1.0f / FXSCALE);
            dis[i] = (dv > 0.0f) ? rsqrtf(dv) : 0.0f;
        }
        s[t] = cv;
        __syncthreads();
        for (int o = 128; o > 0; o >>= 1) {
            if (t < o) s[t] += s[t + o];
            __syncthreads();
        }
        if (t == 0) bsum[bid] = s[0];
    }
    gridbar(barcnt, 2 * FGRID);

    // ---- phase 2b: block 0 scans bsum[G] (exclusive) ----
    if (bid == 0) {
        int v = (t < G) ? bsum[t] : 0;
        s[t] = v;
        __syncthreads();
        for (int o = 1; o < 256; o <<= 1) {
            int u = (t >= o) ? s[t - o] : 0;
            __syncthreads();
            s[t] += u;
            __syncthreads();
        }
        if (t < G) bsum[t] = s[t] - v;
        if (t == 255) rowptr[N] = s[255];
    }
    gridbar(barcnt, 3 * FGRID);

    // ---- phase 2c: per-row rowptr + xg = bf16(dis .* x) ----
    if (bid < G) {
        int i = bid * 256 + t;
        int v = (i < N) ? (int)(cd[i] >> 44) : 0;
        s[t] = v;
        __syncthreads();
        for (int o = 1; o < 256; o <<= 1) {
            int u = (t >= o) ? s[t - o] : 0;
            __syncthreads();
            s[t] += u;
            __syncthreads();
        }
        if (i < N) rowptr[i] = bsum[bid] + s[t] - v;
    }
    for (int i4 = gtid; i4 < N * 16; i4 += FT) {   // N*C/4 float4s
        int r = i4 >> 4;
        float di = dis[r];
        float4 vv = *(const float4*)(x + (size_t)i4 * 4);
        ushort4 o;
        o.x = f2bf_rne(vv.x * di); o.y = f2bf_rne(vv.y * di);
        o.z = f2bf_rne(vv.z * di); o.w = f2bf_rne(vv.w * di);
        *(ushort4*)(xg + (size_t)i4 * 4) = o;
    }
    gridbar(barcnt, 4 * FGRID);

    // ---- phase 3: atomic-free scatter into CSR (packed u32 edges) ----
    for (int e = gtid; e < E; e += FT) {
        int r = row[e];
        unsigned pk = ((unsigned)col[e] << 16) | (unsigned)f2bf_rne(ew[e]);
        epk[rowptr[r] + (int)rank16[e]] = pk;
    }
}

// --- CSR SpMM, 2 edges/wave (half-wave each), packed u32 edges,
// bf16x2 gathers of the dis-prescaled operand. out32 = -dis_r * S;
// outbf = bf16(dis_r * out32) for the next propagation.
__global__ __launch_bounds__(256) void spmm_csr_kernel(
        const int* __restrict__ rowptr,
        const unsigned* __restrict__ epk,   // (col<<16)|bf16(ew)
        const float* __restrict__ dis,
        const unsigned* __restrict__ h32,   // bf16x2 [N][32], pre-scaled by dis
        float* __restrict__ out32,          // fp32 [N][C]
        unsigned* __restrict__ outbf,       // bf16x2 [N][32]
        int N, int writebf) {
    int wid = (blockIdx.x * blockDim.x + threadIdx.x) >> 6;  // row id
    int lane = threadIdx.x & 63;
    if (wid >= N) return;
    int half = lane >> 5;        // which edge of the pair
    int cp   = lane & 31;        // channel pair 0..31
    int beg = rowptr[wid];
    int end = rowptr[wid + 1];
    float ax0 = 0.f, ay0 = 0.f, ax1 = 0.f, ay1 = 0.f;
    float ax2 = 0.f, ay2 = 0.f, ax3 = 0.f, ay3 = 0.f;
    for (int base = beg; base < end; base += 64) {
        int idx = base + lane;
        unsigned ed = (idx < end) ? epk[idx] : 0u;  // pad: w=0,col=0
        int cnt = end - base; if (cnt > 64) cnt = 64;
        for (int j = 0; j < cnt; j += 8) {
            unsigned e0 = (unsigned)__shfl((int)ed, j + half);
            unsigned e1 = (unsigned)__shfl((int)ed, j + 2 + half);
            unsigned e2 = (unsigned)__shfl((int)ed, j + 4 + half);
            unsigned e3 = (unsigned)__shfl((int)ed, j + 6 + half);
            float w0 = bf2f((u16)(e0 & 0xffffu)); int c0 = (int)(e0 >> 16);
            float w1 = bf2f((u16)(e1 & 0xffffu)); int c1 = (int)(e1 >> 16);
            float w2 = bf2f((u16)(e2 & 0xffffu)); int c2 = (int)(e2 >> 16);
            float w3 = bf2f((u16)(e3 & 0xffffu)); int c3 = (int)(e3 >> 16);
            unsigned hv0 = h32[(size_t)c0 * 32 + cp];
            unsigned hv1 = h32[(size_t)c1 * 32 + cp];
            unsigned hv2 = h32[(size_t)c2 * 32 + cp];
            unsigned hv3 = h32[(size_t)c3 * 32 + cp];
            ax0 = fmaf(w0, bf2f((u16)(hv0 & 0xffffu)), ax0);
            ay0 = fmaf(w0, bf2f((u16)(hv0 >> 16)),     ay0);
            ax1 = fmaf(w1, bf2f((u16)(hv1 & 0xffffu)), ax1);
            ay1 = fmaf(w1, bf2f((u16)(hv1 >> 16)),     ay1);
            ax2 = fmaf(w2, bf2f((u16)(hv2 & 0xffffu)), ax2);
            ay2 = fmaf(w2, bf2f((u16)(hv2 >> 16)),     ay2);
            ax3 = fmaf(w3, bf2f((u16)(hv3 & 0xffffu)), ax3);
            ay3 = fmaf(w3, bf2f((u16)(hv3 >> 16)),     ay3);
        }
    }
    float ax = (ax0 + ax1) + (ax2 + ax3);
    float ay = (ay0 + ay1) + (ay2 + ay3);
    float bx = __shfl(ax, cp + 32);
    float by = __shfl(ay, cp + 32);
    if (half == 0) {
        float dr = dis[wid];
        float rx = -dr * (ax + bx);
        float ry = -dr * (ay + by);
        *(float2*)(out32 + (size_t)wid * C + 2 * cp) = make_float2(rx, ry);
        if (writebf) {
            unsigned pk = (unsigned)f2bf_rne(dr * rx) | ((unsigned)f2bf_rne(dr * ry) << 16);
            outbf[(size_t)wid * 32 + cp] = pk;
        }
    }
}

// --- Fused dense epilogue as register-tiled GEMM ---
// out = relu([x | T1 | 2P-x] @ Wcat + b), Wcat = [192][64] (W row-major)
__global__ __launch_bounds__(256) void final_gemm_kernel(
        const float* __restrict__ x,
        const float* __restrict__ T1,
        const float* __restrict__ P,
        const float* __restrict__ W,   // [192][64] row-major
        const float* __restrict__ b,
        float* __restrict__ out, int N) {
    __shared__ float As[16][64];  // [k][node]
    __shared__ float Ws[16][64];  // [k][col]

    int t  = threadIdx.x;
    int tx = t & 15;
    int ty = t >> 4;
    int n0 = blockIdx.x * 64;

    int sn = t >> 2;
    int skb = (t & 3) * 4;

    float acc[4][4];
#pragma unroll
    for (int i = 0; i < 4; i++)
#pragma unroll
        for (int j = 0; j < 4; j++) acc[i][j] = 0.0f;

#pragma unroll 1
    for (int s = 0; s < 12; s++) {
        float4 wv = *(const float4*)(W + s * 1024 + t * 4);
        int nn = n0 + sn;
        float4 av = make_float4(0.f, 0.f, 0.f, 0.f);
        if (nn < N) {
            if (s < 4) {
                av = *(const float4*)(x + (size_t)nn * C + s * 16 + skb);
            } else if (s < 8) {
                av = *(const float4*)(T1 + (size_t)nn * C + (s - 4) * 16 + skb);
            } else {
                float4 pv = *(const float4*)(P + (size_t)nn * C + (s - 8) * 16 + skb);
                float4 xv = *(const float4*)(x + (size_t)nn * C + (s - 8) * 16 + skb);
                av = make_float4(2.0f * pv.x - xv.x, 2.0f * pv.y - xv.y,
                                 2.0f * pv.z - xv.z, 2.0f * pv.w - xv.w);
            }
        }
        __syncthreads();
        {
            int wk = (t * 4) >> 6;
            int wc = (t * 4) & 63;
            *(float4*)&Ws[wk][wc] = wv;
        }
        As[skb + 0][sn] = av.x;
        As[skb + 1][sn] = av.y;
        As[skb + 2][sn] = av.z;
        As[skb + 3][sn] = av.w;
        __syncthreads();

#pragma unroll
        for (int kk = 0; kk < 16; kk++) {
            float4 a4 = *(const float4*)&As[kk][ty * 4];
            float4 w4 = *(const float4*)&Ws[kk][tx * 4];
            float ar[4] = {a4.x, a4.y, a4.z, a4.w};
            float wr[4] = {w4.x, w4.y, w4.z, w4.w};
#pragma unroll
            for (int i = 0; i < 4; i++)
#pragma unroll
                for (int j = 0; j < 4; j++)
                    acc[i][j] = fmaf(ar[i], wr[j], acc[i][j]);
        }
    }

    float4 bv = *(const float4*)(b + tx * 4);
    float br[4] = {bv.x, bv.y, bv.z, bv.w};
#pragma unroll
    for (int i = 0; i < 4; i++) {
        int node = n0 + ty * 4 + i;
        if (node < N) {
            float4 o;
            o.x = fmaxf(acc[i][0] + br[0], 0.0f);
            o.y = fmaxf(acc[i][1] + br[1], 0.0f);
            o.z = fmaxf(acc[i][2] + br[2], 0.0f);
            o.w = fmaxf(acc[i][3] + br[3], 0.0f);
            *(float4*)(out + (size_t)node * C + tx * 4) = o;
        }
    }
}

extern "C" void kernel_launch(void* const* d_in, const int* in_sizes, int n_in,
                              void* d_out, int out_size, void* d_ws, size_t ws_size,
                              hipStream_t stream) {
    const float* x  = (const float*)d_in[0];
    const int*   ei = (const int*)d_in[1];
    const float* ew = (const float*)d_in[2];
    const float* W  = (const float*)d_in[3];
    const float* b  = (const float*)d_in[4];
    float* out = (float*)d_out;

    int N = in_sizes[0] / C;
    int E = in_sizes[2];
    const int* row = ei;        // edge_index[0]
    const int* col = ei + E;    // edge_index[1]

    char* ws = (char*)d_ws;
    size_t off = 0;
    auto alloc = [&](size_t bytes) {
        void* p = ws + off;
        off = (off + bytes + 255) & ~(size_t)255;
        return p;
    };
    // barcnt + cd contiguous -> one memsetAsync zeroes both
    int*      barcnt = (int*)alloc(4);
    unsigned long long* cd = (unsigned long long*)alloc((size_t)N * 8);
    size_t zero_bytes = off;           // covers barcnt..cd
    int*      rowptr = (int*)alloc((size_t)(N + 1) * 4);
    int*      bsum   = (int*)alloc((size_t)256 * 4);
    u16*      rank16 = (u16*)alloc((size_t)E * 2);
    unsigned* epk    = (unsigned*)alloc((size_t)E * 4);
    float*    dis    = (float*)alloc((size_t)N * 4);
    float*    T1     = (float*)alloc((size_t)N * C * 4);
    float*    P      = (float*)alloc((size_t)N * C * 4);
    u16*      xg     = (u16*)alloc((size_t)N * C * 2);
    u16*      T1g    = (u16*)alloc((size_t)N * C * 2);

    hipMemsetAsync(ws, 0, zero_bytes, stream);

    frontend_kernel<<<FGRID, 256, 0, stream>>>(x, row, col, ew, barcnt, cd,
                                               rowptr, bsum, rank16, epk,
                                               dis, xg, E, N);

    const int B = 256;
    int spmm_blocks = (int)(((long long)N * 64 + B - 1) / B);
    spmm_csr_kernel<<<spmm_blocks, B, 0, stream>>>(rowptr, epk, dis,
                                                   (const unsigned*)xg,
                                                   T1, (unsigned*)T1g, N, 1);
    spmm_csr_kernel<<<spmm_blocks, B, 0, stream>>>(rowptr, epk, dis,
                                                   (const unsigned*)T1g,
                                                   P, (unsigned*)T1g, N, 0);

    final_gemm_kernel<<<(N + 63) / 64, B, 0, stream>>>(x, T1, P, W, b, out, N);
}

// Round 13
// 215.366 us; speedup vs baseline: 1.2897x; 1.2897x over previous
//
#include <hip/hip_runtime.h>
#include <hip/hip_bf16.h>

#define C 64   // C_IN == C_OUT == 64
#define FXSCALE 16777216.0f            // 2^24
#define LOW44 ((1ULL << 44) - 1)

typedef unsigned short u16;

__device__ __forceinline__ u16 f2bf_rne(float v) {
    unsigned u = __float_as_uint(v);
    u += 0x7FFFu + ((u >> 16) & 1u);
    return (u16)(u >> 16);
}
__device__ __forceinline__ float bf2f(u16 u) {
    return __uint_as_float((unsigned)u << 16);
}

// --- Kernel 1: histogram (x4 unrolled, full occupancy). One u64 atomic/edge:
// bits [44:63] = count, [0:43] = fixed-point sum(ew). Return -> global rank.
__global__ __launch_bounds__(256) void hist_kernel(const int* __restrict__ row,
                                                   const float* __restrict__ ew,
                                                   unsigned long long* __restrict__ cd,
                                                   u16* __restrict__ rank16,
                                                   int E) {
    int t = threadIdx.x;
    int base = blockIdx.x * 1024;
    unsigned long long old[4];
    int e[4];
#pragma unroll
    for (int u = 0; u < 4; u++) {
        e[u] = base + u * 256 + t;
        if (e[u] < E) {
            int r = row[e[u]];
            unsigned long long fx = (unsigned long long)__float2uint_rn(ew[e[u]] * FXSCALE);
            old[u] = atomicAdd(&cd[r], (1ULL << 44) | fx);
        }
    }
#pragma unroll
    for (int u = 0; u < 4; u++) {
        if (e[u] < E) rank16[e[u]] = (u16)(old[u] >> 44);
    }
}

// --- Kernel 2: fused scan. Grid = G (196) <= 256 CUs -> all blocks
// co-resident; each publishes its tile total, spins for all aggregates
// (flat, no chaining), then writes rowptr, dis, and xg = bf16(dis.*x).
__global__ __launch_bounds__(256) void scan_kernel(
        const unsigned long long* __restrict__ cd,
        unsigned long long* __restrict__ status,   // zeroed
        int* __restrict__ rowptr,
        float* __restrict__ dis,
        const float* __restrict__ x,
        u16* __restrict__ xg,
        int N, int G) {
    __shared__ int s[256];
    __shared__ float sdis[256];
    int t = threadIdx.x;
    int bid = blockIdx.x;
    int i = bid * 256 + t;

    int cnt = 0;
    float di = 0.0f;
    if (i < N) {
        unsigned long long v = cd[i];
        cnt = (int)(v >> 44);
        float dv = (float)(v & LOW44) * (1.0f / FXSCALE);
        di = (dv > 0.0f) ? rsqrtf(dv) : 0.0f;
        dis[i] = di;
    }
    sdis[t] = di;
    s[t] = cnt;
    __syncthreads();
    // inclusive scan of counts within tile
    for (int o = 1; o < 256; o <<= 1) {
        int u = (t >= o) ? s[t - o] : 0;
        __syncthreads();
        s[t] += u;
        __syncthreads();
    }
    int tile_total = s[255];
    int my_excl = s[t] - cnt;

    // publish aggregate; spin for all tiles' aggregates
    if (t == 0) {
        __threadfence();
        atomicExch(&status[bid], (1ULL << 32) | (unsigned)tile_total);
    }
    int val = 0;
    if (t < G) {
        unsigned long long v;
        do {
            v = atomicAdd(&status[t], 0ULL);
        } while ((v >> 32) == 0);
        val = (int)(v & 0xffffffffULL);
    }
    __syncthreads();        // protect s[] reuse
    s[t] = val;
    __syncthreads();
    for (int o = 1; o < 256; o <<= 1) {
        int u = (t >= o) ? s[t - o] : 0;
        __syncthreads();
        s[t] += u;
        __syncthreads();
    }
    int prefix = s[bid] - tile_total;       // exclusive tile prefix
    if (i < N) rowptr[i] = prefix + my_excl;
    if (bid == 0 && t == 0) rowptr[N] = s[G - 1];

    // xg = bf16(dis .* x) for this tile's 256 rows (coalesced float4)
    size_t nb = (size_t)bid * 16384;
#pragma unroll 1
    for (int it = 0; it < 16; it++) {
        int idx4 = it * 256 + t;            // 0..4095
        int lr = idx4 >> 4;
        if (bid * 256 + lr < N) {
            float4 vv = *(const float4*)(x + nb + (size_t)idx4 * 4);
            float d2 = sdis[lr];
            ushort4 o;
            o.x = f2bf_rne(vv.x * d2); o.y = f2bf_rne(vv.y * d2);
            o.z = f2bf_rne(vv.z * d2); o.w = f2bf_rne(vv.w * d2);
            *(ushort4*)(xg + nb + (size_t)idx4 * 4) = o;
        }
    }
}

// --- Kernel 3: atomic-free scatter: pos = rowptr[r] + rank16[e] ---
__global__ __launch_bounds__(256) void scatter_kernel(const int* __restrict__ row,
                                                      const int* __restrict__ col,
                                                      const float* __restrict__ ew,
                                                      const int* __restrict__ rowptr,
                                                      const u16* __restrict__ rank16,
                                                      unsigned* __restrict__ epk,
                                                      int E) {
    int t = threadIdx.x;
    int base = blockIdx.x * 1024;
#pragma unroll
    for (int u = 0; u < 4; u++) {
        int e = base + u * 256 + t;
        if (e < E) {
            int r = row[e];
            unsigned pk = ((unsigned)col[e] << 16) | (unsigned)f2bf_rne(ew[e]);
            epk[rowptr[r] + (int)rank16[e]] = pk;
        }
    }
}

// shared spmm inner body: accumulate one row, return (rx, ry) for half==0
__device__ __forceinline__ float2 spmm_row(
        const int* __restrict__ rowptr,
        const unsigned* __restrict__ epk,
        const unsigned* __restrict__ h32,
        float dr, int wid, int lane, int half, int cp) {
    int beg = rowptr[wid];
    int end = rowptr[wid + 1];
    float ax0 = 0.f, ay0 = 0.f, ax1 = 0.f, ay1 = 0.f;
    float ax2 = 0.f, ay2 = 0.f, ax3 = 0.f, ay3 = 0.f;
    for (int base = beg; base < end; base += 64) {
        int idx = base + lane;
        unsigned ed = (idx < end) ? epk[idx] : 0u;  // pad: w=0,col=0
        int cnt = end - base; if (cnt > 64) cnt = 64;
        for (int j = 0; j < cnt; j += 8) {
            unsigned e0 = (unsigned)__shfl((int)ed, j + half);
            unsigned e1 = (unsigned)__shfl((int)ed, j + 2 + half);
            unsigned e2 = (unsigned)__shfl((int)ed, j + 4 + half);
            unsigned e3 = (unsigned)__shfl((int)ed, j + 6 + half);
            float w0 = bf2f((u16)(e0 & 0xffffu)); int c0 = (int)(e0 >> 16);
            float w1 = bf2f((u16)(e1 & 0xffffu)); int c1 = (int)(e1 >> 16);
            float w2 = bf2f((u16)(e2 & 0xffffu)); int c2 = (int)(e2 >> 16);
            float w3 = bf2f((u16)(e3 & 0xffffu)); int c3 = (int)(e3 >> 16);
            unsigned hv0 = h32[(size_t)c0 * 32 + cp];
            unsigned hv1 = h32[(size_t)c1 * 32 + cp];
            unsigned hv2 = h32[(size_t)c2 * 32 + cp];
            unsigned hv3 = h32[(size_t)c3 * 32 + cp];
            ax0 = fmaf(w0, bf2f((u16)(hv0 & 0xffffu)), ax0);
            ay0 = fmaf(w0, bf2f((u16)(hv0 >> 16)),     ay0);
            ax1 = fmaf(w1, bf2f((u16)(hv1 & 0xffffu)), ax1);
            ay1 = fmaf(w1, bf2f((u16)(hv1 >> 16)),     ay1);
            ax2 = fmaf(w2, bf2f((u16)(hv2 & 0xffffu)), ax2);
            ay2 = fmaf(w2, bf2f((u16)(hv2 >> 16)),     ay2);
            ax3 = fmaf(w3, bf2f((u16)(hv3 & 0xffffu)), ax3);
            ay3 = fmaf(w3, bf2f((u16)(hv3 >> 16)),     ay3);
        }
    }
    float ax = (ax0 + ax1) + (ax2 + ax3);
    float ay = (ay0 + ay1) + (ay2 + ay3);
    float bx = __shfl(ax, cp + 32);
    float by = __shfl(ay, cp + 32);
    return make_float2(-dr * (ax + bx), -dr * (ay + by));
}

// --- Kernel 4: spmm1: T1 = L_hat x (fp32 + bf16-prescaled outputs) ---
__global__ __launch_bounds__(256) void spmm1_kernel(
        const int* __restrict__ rowptr,
        const unsigned* __restrict__ epk,
        const float* __restrict__ dis,
        const unsigned* __restrict__ xg32,
        float* __restrict__ T1,
        unsigned* __restrict__ T1g,
        int N) {
    int wid = (blockIdx.x * blockDim.x + threadIdx.x) >> 6;
    int lane = threadIdx.x & 63;
    if (wid >= N) return;
    int half = lane >> 5;
    int cp   = lane & 31;
    float dr = dis[wid];
    float2 r = spmm_row(rowptr, epk, xg32, dr, wid, lane, half, cp);
    if (half == 0) {
        *(float2*)(T1 + (size_t)wid * C + 2 * cp) = r;
        unsigned pk = (unsigned)f2bf_rne(dr * r.x) | ((unsigned)f2bf_rne(dr * r.y) << 16);
        T1g[(size_t)wid * 32 + cp] = pk;
    }
}

// --- Kernel 5: fused spmm2 + dense GEMM epilogue.
// Block = 64 nodes. Phase A: P rows -> LDS (16 KB). Phase B:
// out = relu([x | T1 | 2P-x] @ Wcat + b) with P from LDS.
__global__ __launch_bounds__(256) void spmm2_gemm_kernel(
        const int* __restrict__ rowptr,
        const unsigned* __restrict__ epk,
        const float* __restrict__ dis,
        const unsigned* __restrict__ T1g32,
        const float* __restrict__ x,
        const float* __restrict__ T1,
        const float* __restrict__ W,   // [192][64] row-major
        const float* __restrict__ b,
        float* __restrict__ out, int N) {
    __shared__ float sP[64][64];   // 16 KB
    __shared__ float As[16][64];
    __shared__ float Ws[16][64];

    int t = threadIdx.x;
    int wave = t >> 6;
    int lane = t & 63;
    int half = lane >> 5;
    int cp   = lane & 31;
    int n0 = blockIdx.x * 64;

    // ---- phase A: spmm2 for this block's 64 rows (16 rows per wave) ----
#pragma unroll 1
    for (int rr = 0; rr < 16; rr++) {
        int wid = n0 + wave * 16 + rr;
        if (wid < N) {
            float dr = dis[wid];
            float2 r = spmm_row(rowptr, epk, T1g32, dr, wid, lane, half, cp);
            if (half == 0) {
                sP[wave * 16 + rr][2 * cp]     = r.x;
                sP[wave * 16 + rr][2 * cp + 1] = r.y;
            }
        }
    }
    __syncthreads();

    // ---- phase B: gemm ----
    int tx = t & 15;
    int ty = t >> 4;
    int sn = t >> 2;
    int skb = (t & 3) * 4;

    float acc[4][4];
#pragma unroll
    for (int i = 0; i < 4; i++)
#pragma unroll
        for (int j = 0; j < 4; j++) acc[i][j] = 0.0f;

#pragma unroll 1
    for (int s = 0; s < 12; s++) {
        float4 wv = *(const float4*)(W + s * 1024 + t * 4);
        int nn = n0 + sn;
        float4 av = make_float4(0.f, 0.f, 0.f, 0.f);
        if (nn < N) {
            if (s < 4) {
                av = *(const float4*)(x + (size_t)nn * C + s * 16 + skb);
            } else if (s < 8) {
                av = *(const float4*)(T1 + (size_t)nn * C + (s - 4) * 16 + skb);
            } else {
                float4 pv = *(const float4*)(&sP[sn][(s - 8) * 16 + skb]);
                float4 xv = *(const float4*)(x + (size_t)nn * C + (s - 8) * 16 + skb);
                av = make_float4(2.0f * pv.x - xv.x, 2.0f * pv.y - xv.y,
                                 2.0f * pv.z - xv.z, 2.0f * pv.w - xv.w);
            }
        }
        __syncthreads();
        {
            int wk = (t * 4) >> 6;
            int wc = (t * 4) & 63;
            *(float4*)&Ws[wk][wc] = wv;
        }
        As[skb + 0][sn] = av.x;
        As[skb + 1][sn] = av.y;
        As[skb + 2][sn] = av.z;
        As[skb + 3][sn] = av.w;
        __syncthreads();

#pragma unroll
        for (int kk = 0; kk < 16; kk++) {
            float4 a4 = *(const float4*)&As[kk][ty * 4];
            float4 w4 = *(const float4*)&Ws[kk][tx * 4];
            float ar[4] = {a4.x, a4.y, a4.z, a4.w};
            float wr[4] = {w4.x, w4.y, w4.z, w4.w};
#pragma unroll
            for (int i = 0; i < 4; i++)
#pragma unroll
                for (int j = 0; j < 4; j++)
                    acc[i][j] = fmaf(ar[i], wr[j], acc[i][j]);
        }
    }

    float4 bv = *(const float4*)(b + tx * 4);
    float br[4] = {bv.x, bv.y, bv.z, bv.w};
#pragma unroll
    for (int i = 0; i < 4; i++) {
        int node = n0 + ty * 4 + i;
        if (node < N) {
            float4 o;
            o.x = fmaxf(acc[i][0] + br[0], 0.0f);
            o.y = fmaxf(acc[i][1] + br[1], 0.0f);
            o.z = fmaxf(acc[i][2] + br[2], 0.0f);
            o.w = fmaxf(acc[i][3] + br[3], 0.0f);
            *(float4*)(out + (size_t)node * C + tx * 4) = o;
        }
    }
}

extern "C" void kernel_launch(void* const* d_in, const int* in_sizes, int n_in,
                              void* d_out, int out_size, void* d_ws, size_t ws_size,
                              hipStream_t stream) {
    const float* x  = (const float*)d_in[0];
    const int*   ei = (const int*)d_in[1];
    const float* ew = (const float*)d_in[2];
    const float* W  = (const float*)d_in[3];
    const float* b  = (const float*)d_in[4];
    float* out = (float*)d_out;

    int N = in_sizes[0] / C;
    int E = in_sizes[2];
    const int* row = ei;        // edge_index[0]
    const int* col = ei + E;    // edge_index[1]

    char* ws = (char*)d_ws;
    size_t off = 0;
    auto alloc = [&](size_t bytes) {
        void* p = ws + off;
        off = (off + bytes + 255) & ~(size_t)255;
        return p;
    };
    // cd + status contiguous -> one memsetAsync
    unsigned long long* cd     = (unsigned long long*)alloc((size_t)N * 8);
    unsigned long long* status = (unsigned long long*)alloc((size_t)256 * 8);
    size_t zero_bytes = off;
    int*      rowptr = (int*)alloc((size_t)(N + 1) * 4);
    u16*      rank16 = (u16*)alloc((size_t)E * 2);
    unsigned* epk    = (unsigned*)alloc((size_t)E * 4);
    float*    dis    = (float*)alloc((size_t)N * 4);
    float*    T1     = (float*)alloc((size_t)N * C * 4);
    u16*      xg     = (u16*)alloc((size_t)N * C * 2);
    u16*      T1g    = (u16*)alloc((size_t)N * C * 2);

    hipMemsetAsync(ws, 0, zero_bytes, stream);

    const int B = 256;
    const int G = (N + 255) / 256;      // 196
    int edgeBlocks = (E + 1023) / 1024; // 782

    hist_kernel<<<edgeBlocks, B, 0, stream>>>(row, ew, cd, rank16, E);
    scan_kernel<<<G, B, 0, stream>>>(cd, status, rowptr, dis, x, xg, N, G);
    scatter_kernel<<<edgeBlocks, B, 0, stream>>>(row, col, ew, rowptr, rank16,
                                                 epk, E);

    int spmm_blocks = (int)(((long long)N * 64 + B - 1) / B);
    spmm1_kernel<<<spmm_blocks, B, 0, stream>>>(rowptr, epk, dis,
                                                (const unsigned*)xg,
                                                T1, (unsigned*)T1g, N);
    spmm2_gemm_kernel<<<(N + 63) / 64, B, 0, stream>>>(rowptr, epk, dis,
                                                       (const unsigned*)T1g,
                                                       x, T1, W, b, out, N);
}